// Round 2
// baseline (734.044 us; speedup 1.0000x reference)
//
#include <hip/hip_runtime.h>
#include <hip/hip_bf16.h>

typedef unsigned short u16;
typedef __attribute__((ext_vector_type(8))) short bf16x8;   // 8 bf16 = 4 VGPRs (MFMA A/B operand)
typedef __attribute__((ext_vector_type(4))) float f32x4;    // MFMA C/D
typedef __attribute__((ext_vector_type(4))) u16 u16x4;

#define DEV __device__ __forceinline__

constexpr int B_ = 4, S_ = 2048, H_ = 16, DK_ = 64, DM_ = 1024;
constexpr int M_ = B_ * S_;  // 8192 rows for all GEMMs

DEV u16 f2bf(float x) {  // RNE fp32 -> bf16
  union { float f; unsigned u; } v; v.f = x;
  return (u16)((v.u + 0x7fffu + ((v.u >> 16) & 1u)) >> 16);
}

DEV bf16x8 ld16(const u16* p) { return *(const bf16x8*)p; }

DEV void g2l16(const void* g, void* l) {  // async global->LDS, 16B/lane, linear dest
  __builtin_amdgcn_global_load_lds((const __attribute__((address_space(1))) void*)g,
                                   (__attribute__((address_space(3))) void*)l, 16, 0, 0);
}

// ---------------- fp32 -> bf16 convert (4 elems/thread, exact coverage) ----------------
__global__ __launch_bounds__(256) void cvt_kernel(const float* __restrict__ in,
                                                  u16* __restrict__ out) {
  int i = (blockIdx.x * 256 + threadIdx.x) * 4;
  float4 v = *(const float4*)(in + i);
  u16x4 o; o[0] = f2bf(v.x); o[1] = f2bf(v.y); o[2] = f2bf(v.z); o[3] = f2bf(v.w);
  *(u16x4*)(out + i) = o;
}

// ---------------- weight transpose-convert: W[K][N] fp32 -> Wt[N][K] bf16 ----------------
__global__ __launch_bounds__(256) void wtrans_kernel(const float* __restrict__ W,
                                                     u16* __restrict__ Wt) {
  __shared__ u16 t[64][68];
  const int r0 = blockIdx.y * 64, c0 = blockIdx.x * 64;
  const int lr = threadIdx.x >> 4;         // 0..15
  const int lc = (threadIdx.x & 15) * 4;   // 0..60
#pragma unroll
  for (int i = 0; i < 4; ++i) {
    int row = i * 16 + lr;
    float4 v = *(const float4*)(W + (size_t)(r0 + row) * DM_ + c0 + lc);
    t[lc + 0][row] = f2bf(v.x); t[lc + 1][row] = f2bf(v.y);
    t[lc + 2][row] = f2bf(v.z); t[lc + 3][row] = f2bf(v.w);
  }
  __syncthreads();
#pragma unroll
  for (int i = 0; i < 4; ++i) {
    int c = i * 16 + lr;
    u16x4 o; o[0] = t[c][lc]; o[1] = t[c][lc + 1]; o[2] = t[c][lc + 2]; o[3] = t[c][lc + 3];
    *(u16x4*)(Wt + (size_t)(c0 + c) * DM_ + r0 + lc) = o;
  }
}

// ---------------- GEMM: X[M][1024] bf16 x Wt[1024 n][1024 k] bf16 ----------------
// OUT_MODE 0: fp32 [M][1024] row-major (final out-proj)
// OUT_MODE 1: bf16 scattered to [b][h][s][d] (Q/K projections)
// OUT_MODE 2: bf16 scattered to [b][h][d][s] (V projection, pre-transposed for PV)
template <int OUT_MODE>
__global__ __launch_bounds__(256) void gemm_bt(const u16* __restrict__ X,
                                               const u16* __restrict__ Wt,
                                               void* __restrict__ outp) {
  constexpr int K = 1024, N = 1024;
  __shared__ u16 As[128 * 64];
  __shared__ u16 Bs[128 * 64];
  const int tid = threadIdx.x;
  const int w = tid >> 6, lane = tid & 63;
  const int l15 = lane & 15, lg = lane >> 4;
  const int m0 = blockIdx.y * 128, n0 = blockIdx.x * 128;
  const int wm = (w >> 1) * 64, wn = (w & 1) * 64;
  f32x4 acc[4][4] = {};

  const int srow = lane >> 3;        // row within 8-row LDS chunk
  const int scol = (lane & 7) * 8;   // k offset within tile

  for (int kt = 0; kt < K; kt += 64) {
#pragma unroll
    for (int i = 0; i < 4; ++i) {
      const int chunk = w * 4 + i;          // 16 chunks x 1KB cover the 16KB tile
      const int row = chunk * 8 + srow;
      g2l16(X + (size_t)(m0 + row) * K + kt + scol, As + chunk * 512);
      g2l16(Wt + (size_t)(n0 + row) * K + kt + scol, Bs + chunk * 512);
    }
    __syncthreads();
#pragma unroll
    for (int kk = 0; kk < 2; ++kk) {
      bf16x8 a[4], b[4];
#pragma unroll
      for (int i = 0; i < 4; ++i)
        a[i] = ld16(As + (wm + i * 16 + l15) * 64 + kk * 32 + lg * 8);
#pragma unroll
      for (int j = 0; j < 4; ++j)
        b[j] = ld16(Bs + (wn + j * 16 + l15) * 64 + kk * 32 + lg * 8);
#pragma unroll
      for (int i = 0; i < 4; ++i)
#pragma unroll
        for (int j = 0; j < 4; ++j)
          acc[i][j] = __builtin_amdgcn_mfma_f32_16x16x32_bf16(a[i], b[j], acc[i][j], 0, 0, 0);
    }
    __syncthreads();
  }
  // epilogue: C/D layout col=lane&15, row=(lane>>4)*4+r  [m89-verified]
#pragma unroll
  for (int i = 0; i < 4; ++i)
#pragma unroll
    for (int j = 0; j < 4; ++j) {
      if (OUT_MODE == 2) {
        // 4 consecutive s values per lane -> one 8B store into Vt[bh][d][s]
        int m = m0 + wm + i * 16 + lg * 4;   // s base (block rows never cross b)
        int n = n0 + wn + j * 16 + l15;
        int b = m >> 11, s = m & 2047;
        int h = n >> 6, d = n & 63;
        u16x4 o;
#pragma unroll
        for (int r = 0; r < 4; ++r) o[r] = f2bf(acc[i][j][r]);
        *(u16x4*)((u16*)outp + ((size_t)(b * H_ + h) * DK_ + d) * S_ + s) = o;
      } else {
#pragma unroll
        for (int r = 0; r < 4; ++r) {
          int m = m0 + wm + i * 16 + lg * 4 + r;
          int n = n0 + wn + j * 16 + l15;
          if (OUT_MODE == 0) {
            ((float*)outp)[(size_t)m * N + n] = acc[i][j][r];
          } else {
            int b = m >> 11, s = m & 2047;
            int h = n >> 6, d = n & 63;
            ((u16*)outp)[((size_t)(b * H_ + h) * S_ + s) * DK_ + d] = f2bf(acc[i][j][r]);
          }
        }
      }
    }
}

// ---------------- flash attention ----------------
// grid (S/64, B*H), 256 threads = 4 waves; wave owns 16 q-rows.
// Qh,Kh: [bh][S][64] bf16 ; Vt: [bh][64][S] bf16 ; ctx out: [b][s][h*64+d] bf16
__global__ __launch_bounds__(256) void attn_kernel(const u16* __restrict__ Qh,
                                                   const u16* __restrict__ Kh,
                                                   const u16* __restrict__ Vt,
                                                   u16* __restrict__ ctx) {
  __shared__ u16 plds[4 * 16 * 64];  // per-wave 16x64 P tile (XOR-swizzled)
  const int tid = threadIdx.x;
  const int w = tid >> 6, lane = tid & 63;
  const int l15 = lane & 15, lg = lane >> 4;
  const int bh = blockIdx.y;
  const int q0 = blockIdx.x * 64 + w * 16;

  const u16* Qp = Qh + ((size_t)bh * S_ + q0 + l15) * DK_ + lg * 8;
  const bf16x8 qf0 = ld16(Qp);
  const bf16x8 qf1 = ld16(Qp + 32);

  f32x4 accO[4] = {};
  float m2[4] = {-1e30f, -1e30f, -1e30f, -1e30f};
  float lsum[4] = {};

  const u16* Kb = Kh + (size_t)bh * S_ * DK_;
  const u16* Vb = Vt + (size_t)bh * DK_ * S_;
  u16* pw = plds + w * 1024;
  const float SC = 0.125f * 1.44269504088896f;  // 1/sqrt(64) * log2(e)

  for (int kv = 0; kv < S_; kv += 64) {
    f32x4 accS[4] = {};
#pragma unroll
    for (int n = 0; n < 4; ++n) {
      const u16* kp = Kb + (size_t)(kv + n * 16 + l15) * DK_ + lg * 8;
      accS[n] = __builtin_amdgcn_mfma_f32_16x16x32_bf16(qf0, ld16(kp), accS[n], 0, 0, 0);
      accS[n] = __builtin_amdgcn_mfma_f32_16x16x32_bf16(qf1, ld16(kp + 32), accS[n], 0, 0, 0);
    }
    // online softmax in exp2 domain; row = lg*4+r, cols spread over 16-lane group x 4 accs
    float mnew[4], scl[4], rs[4];
#pragma unroll
    for (int r = 0; r < 4; ++r) {
      float a = fmaxf(fmaxf(accS[0][r], accS[1][r]), fmaxf(accS[2][r], accS[3][r]));
      a = fmaxf(a, __shfl_xor(a, 1)); a = fmaxf(a, __shfl_xor(a, 2));
      a = fmaxf(a, __shfl_xor(a, 4)); a = fmaxf(a, __shfl_xor(a, 8));
      mnew[r] = fmaxf(m2[r], a * SC);
      scl[r] = exp2f(m2[r] - mnew[r]);
      rs[r] = 0.f;
    }
    float p[4][4];
#pragma unroll
    for (int n = 0; n < 4; ++n)
#pragma unroll
      for (int r = 0; r < 4; ++r) {
        p[n][r] = exp2f(accS[n][r] * SC - mnew[r]);
        rs[r] += p[n][r];
      }
#pragma unroll
    for (int r = 0; r < 4; ++r) {
      float s = rs[r];
      s += __shfl_xor(s, 1); s += __shfl_xor(s, 2);
      s += __shfl_xor(s, 4); s += __shfl_xor(s, 8);
      lsum[r] = lsum[r] * scl[r] + s;
      m2[r] = mnew[r];
    }
#pragma unroll
    for (int dt = 0; dt < 4; ++dt)
#pragma unroll
      for (int r = 0; r < 4; ++r) accO[dt][r] *= scl[r];
    // P -> LDS, 16B-chunk XOR swizzle (both sides) kills bank conflicts
#pragma unroll
    for (int n = 0; n < 4; ++n)
#pragma unroll
      for (int r = 0; r < 4; ++r) {
        int row = lg * 4 + r;
        int col = n * 16 + l15;
        int sw = (((col >> 3) ^ (row & 7)) << 3) + (col & 7);
        pw[row * 64 + sw] = f2bf(p[n][r]);
      }
    // PV: A = P (rows of LDS tile), B = Vt rows (contiguous 16B)
#pragma unroll
    for (int t = 0; t < 2; ++t) {
      int chunk = t * 4 + lg;
      bf16x8 pa = ld16(pw + l15 * 64 + (((chunk ^ (l15 & 7)) << 3)));
#pragma unroll
      for (int dt = 0; dt < 4; ++dt) {
        const u16* vp = Vb + (size_t)(dt * 16 + l15) * S_ + kv + t * 32 + lg * 8;
        accO[dt] = __builtin_amdgcn_mfma_f32_16x16x32_bf16(pa, ld16(vp), accO[dt], 0, 0, 0);
      }
    }
  }
  // epilogue: ctx[b][s][h*64+d]
  const int b = bh >> 4, h = bh & 15;
#pragma unroll
  for (int dt = 0; dt < 4; ++dt)
#pragma unroll
    for (int r = 0; r < 4; ++r) {
      int s = q0 + lg * 4 + r;
      int d = dt * 16 + l15;
      ctx[((size_t)b * S_ + s) * DM_ + h * DK_ + d] = f2bf(accO[dt][r] / lsum[r]);
    }
}

// ---------------- launcher ----------------
// ws high-water: 4 weights (4x2.1MB) + 4 activation buffers (4x16.78MB) = 75.5 MB
extern "C" void kernel_launch(void* const* d_in, const int* in_sizes, int n_in,
                              void* d_out, int out_size, void* d_ws, size_t ws_size,
                              hipStream_t stream) {
  const float* q  = (const float*)d_in[0];
  const float* k  = (const float*)d_in[1];
  const float* v  = (const float*)d_in[2];
  const float* Wq = (const float*)d_in[3];
  const float* Wk = (const float*)d_in[4];
  const float* Wv = (const float*)d_in[5];
  const float* Wo = (const float*)d_in[6];

  char* ws = (char*)d_ws;
  const size_t SZX = (size_t)M_ * DM_ * 2;   // 16.78 MB bf16 activation
  const size_t SZW = (size_t)DM_ * DM_ * 2;  // 2.10 MB bf16 weight
  u16* Wqt = (u16*)(ws);
  u16* Wkt = (u16*)(ws + SZW);
  u16* Wvt = (u16*)(ws + 2 * SZW);
  u16* Wot = (u16*)(ws + 3 * SZW);
  u16* xb  = (u16*)(ws + 4 * SZW);            // q/k/v bf16 (sequential reuse), later ctx
  u16* Qh  = (u16*)(ws + 4 * SZW + SZX);
  u16* Kh  = (u16*)(ws + 4 * SZW + 2 * SZX);
  u16* Vt  = (u16*)(ws + 4 * SZW + 3 * SZX);
  u16* ctx = xb;  // xb free after V projection

  wtrans_kernel<<<dim3(16, 16), 256, 0, stream>>>(Wq, Wqt);
  wtrans_kernel<<<dim3(16, 16), 256, 0, stream>>>(Wk, Wkt);
  wtrans_kernel<<<dim3(16, 16), 256, 0, stream>>>(Wv, Wvt);
  wtrans_kernel<<<dim3(16, 16), 256, 0, stream>>>(Wo, Wot);

  cvt_kernel<<<8192, 256, 0, stream>>>(q, xb);
  gemm_bt<1><<<dim3(8, 64), 256, 0, stream>>>(xb, Wqt, Qh);
  cvt_kernel<<<8192, 256, 0, stream>>>(k, xb);
  gemm_bt<1><<<dim3(8, 64), 256, 0, stream>>>(xb, Wkt, Kh);
  cvt_kernel<<<8192, 256, 0, stream>>>(v, xb);
  gemm_bt<2><<<dim3(8, 64), 256, 0, stream>>>(xb, Wvt, Vt);

  attn_kernel<<<dim3(32, 64), 256, 0, stream>>>(Qh, Kh, Vt, ctx);
  gemm_bt<0><<<dim3(8, 64), 256, 0, stream>>>(ctx, Wot, d_out);
}

// Round 3
// 572.600 us; speedup vs baseline: 1.2820x; 1.2820x over previous
//
#include <hip/hip_runtime.h>
#include <hip/hip_bf16.h>

typedef unsigned short u16;
typedef __attribute__((ext_vector_type(8))) short bf16x8;   // 8 bf16 = 4 VGPRs (MFMA A/B operand)
typedef __attribute__((ext_vector_type(4))) float f32x4;    // 16x16 MFMA C/D
typedef __attribute__((ext_vector_type(16))) float f32x16;  // 32x32 MFMA C/D
typedef __attribute__((ext_vector_type(4))) u16 u16x4;
typedef __attribute__((ext_vector_type(2))) int i32x2;
typedef __attribute__((ext_vector_type(4))) int i32x4;

#define DEV __device__ __forceinline__

constexpr int B_ = 4, S_ = 2048, H_ = 16, DK_ = 64, DM_ = 1024;
constexpr int M_ = B_ * S_;  // 8192 rows for all GEMMs

DEV u16 f2bf(float x) {  // RNE fp32 -> bf16
  union { float f; unsigned u; } v; v.f = x;
  return (u16)((v.u + 0x7fffu + ((v.u >> 16) & 1u)) >> 16);
}

DEV bf16x8 ld16(const u16* p) { return *(const bf16x8*)p; }

DEV void g2l16(const void* g, void* l) {  // async global->LDS, 16B/lane, linear dest
  __builtin_amdgcn_global_load_lds((const __attribute__((address_space(1))) void*)g,
                                   (__attribute__((address_space(3))) void*)l, 16, 0, 0);
}

DEV int cvtpk(float lo, float hi) {  // packed bf16: [15:0]=bf16(lo), [31:16]=bf16(hi)
  int r;
  asm("v_cvt_pk_bf16_f32 %0, %1, %2" : "=v"(r) : "v"(lo), "v"(hi));
  return r;
}

DEV i32x2 pl32swap(int a, int b) {
  // out.x = {a.lo | b.lo-in-hi-lanes}, out.y = {a.hi-in-lo-lanes | b.hi}
  return __builtin_amdgcn_permlane32_swap(a, b, false, false);
}

DEV float asf(int x) { return __builtin_bit_cast(float, x); }
DEV int asi(float x) { return __builtin_bit_cast(int, x); }

// ---------------- fp32 -> bf16 convert (4 elems/thread, exact coverage) ----------------
__global__ __launch_bounds__(256) void cvt_kernel(const float* __restrict__ in,
                                                  u16* __restrict__ out) {
  int i = (blockIdx.x * 256 + threadIdx.x) * 4;
  float4 v = *(const float4*)(in + i);
  u16x4 o; o[0] = f2bf(v.x); o[1] = f2bf(v.y); o[2] = f2bf(v.z); o[3] = f2bf(v.w);
  *(u16x4*)(out + i) = o;
}

// ---------------- weight transpose-convert: W[K][N] fp32 -> Wt[N][K] bf16 ----------------
__global__ __launch_bounds__(256) void wtrans_kernel(const float* __restrict__ W,
                                                     u16* __restrict__ Wt) {
  __shared__ u16 t[64][68];
  const int r0 = blockIdx.y * 64, c0 = blockIdx.x * 64;
  const int lr = threadIdx.x >> 4;         // 0..15
  const int lc = (threadIdx.x & 15) * 4;   // 0..60
#pragma unroll
  for (int i = 0; i < 4; ++i) {
    int row = i * 16 + lr;
    float4 v = *(const float4*)(W + (size_t)(r0 + row) * DM_ + c0 + lc);
    t[lc + 0][row] = f2bf(v.x); t[lc + 1][row] = f2bf(v.y);
    t[lc + 2][row] = f2bf(v.z); t[lc + 3][row] = f2bf(v.w);
  }
  __syncthreads();
#pragma unroll
  for (int i = 0; i < 4; ++i) {
    int c = i * 16 + lr;
    u16x4 o; o[0] = t[c][lc]; o[1] = t[c][lc + 1]; o[2] = t[c][lc + 2]; o[3] = t[c][lc + 3];
    *(u16x4*)(Wt + (size_t)(c0 + c) * DM_ + r0 + lc) = o;
  }
}

// ---------------- GEMM: X[M][1024] bf16 x Wt[1024 n][1024 k] bf16 ----------------
// OUT_MODE 0: fp32 [M][1024] row-major (final out-proj)
// OUT_MODE 1: bf16 scattered to [b][h][s][d] (Q/K projections)
// OUT_MODE 2: bf16 scattered to [b][h][d][s] (V projection, pre-transposed for PV)
template <int OUT_MODE>
__global__ __launch_bounds__(256) void gemm_bt(const u16* __restrict__ X,
                                               const u16* __restrict__ Wt,
                                               void* __restrict__ outp) {
  constexpr int K = 1024, N = 1024;
  __shared__ u16 As[128 * 64];
  __shared__ u16 Bs[128 * 64];
  const int tid = threadIdx.x;
  const int w = tid >> 6, lane = tid & 63;
  const int l15 = lane & 15, lg = lane >> 4;
  const int m0 = blockIdx.y * 128, n0 = blockIdx.x * 128;
  const int wm = (w >> 1) * 64, wn = (w & 1) * 64;
  f32x4 acc[4][4] = {};

  const int srow = lane >> 3;        // row within 8-row LDS chunk
  const int scol = (lane & 7) * 8;   // k offset within tile

  for (int kt = 0; kt < K; kt += 64) {
#pragma unroll
    for (int i = 0; i < 4; ++i) {
      const int chunk = w * 4 + i;          // 16 chunks x 1KB cover the 16KB tile
      const int row = chunk * 8 + srow;
      g2l16(X + (size_t)(m0 + row) * K + kt + scol, As + chunk * 512);
      g2l16(Wt + (size_t)(n0 + row) * K + kt + scol, Bs + chunk * 512);
    }
    __syncthreads();
#pragma unroll
    for (int kk = 0; kk < 2; ++kk) {
      bf16x8 a[4], b[4];
#pragma unroll
      for (int i = 0; i < 4; ++i)
        a[i] = ld16(As + (wm + i * 16 + l15) * 64 + kk * 32 + lg * 8);
#pragma unroll
      for (int j = 0; j < 4; ++j)
        b[j] = ld16(Bs + (wn + j * 16 + l15) * 64 + kk * 32 + lg * 8);
#pragma unroll
      for (int i = 0; i < 4; ++i)
#pragma unroll
        for (int j = 0; j < 4; ++j)
          acc[i][j] = __builtin_amdgcn_mfma_f32_16x16x32_bf16(a[i], b[j], acc[i][j], 0, 0, 0);
    }
    __syncthreads();
  }
  // epilogue: C/D layout col=lane&15, row=(lane>>4)*4+r  [m89-verified]
#pragma unroll
  for (int i = 0; i < 4; ++i)
#pragma unroll
    for (int j = 0; j < 4; ++j) {
      if (OUT_MODE == 2) {
        // 4 consecutive s values per lane -> one 8B store into Vt[bh][d][s]
        int m = m0 + wm + i * 16 + lg * 4;   // s base (block rows never cross b)
        int n = n0 + wn + j * 16 + l15;
        int b = m >> 11, s = m & 2047;
        int h = n >> 6, d = n & 63;
        u16x4 o;
#pragma unroll
        for (int r = 0; r < 4; ++r) o[r] = f2bf(acc[i][j][r]);
        *(u16x4*)((u16*)outp + ((size_t)(b * H_ + h) * DK_ + d) * S_ + s) = o;
      } else {
#pragma unroll
        for (int r = 0; r < 4; ++r) {
          int m = m0 + wm + i * 16 + lg * 4 + r;
          int n = n0 + wn + j * 16 + l15;
          if (OUT_MODE == 0) {
            ((float*)outp)[(size_t)m * N + n] = acc[i][j][r];
          } else {
            int b = m >> 11, s = m & 2047;
            int h = n >> 6, d = n & 63;
            ((u16*)outp)[((size_t)(b * H_ + h) * S_ + s) * DK_ + d] = f2bf(acc[i][j][r]);
          }
        }
      }
    }
}

// ---------------- flash attention (m214-class: swapped QK^T + swapped PV, in-reg softmax) ----
// grid (S/128, B*H), 256 threads = 4 waves; each wave owns 32 q-rows. No LDS, no barriers.
// Qh,Kh: [bh][S][64] bf16 ; Vt: [bh][64][S] bf16 ; ctx out: [b][s][h*64+d] bf16
__global__ __launch_bounds__(256) void attn_kernel(const u16* __restrict__ Qh,
                                                   const u16* __restrict__ Kh,
                                                   const u16* __restrict__ Vt,
                                                   u16* __restrict__ ctx) {
  const int lane = threadIdx.x & 63, w = threadIdx.x >> 6;
  const int l31 = lane & 31, hi = lane >> 5;
  const int bh = blockIdx.y;
  const int q0 = blockIdx.x * 128 + w * 32;

  const u16* Qb = Qh + (size_t)bh * S_ * DK_;
  const u16* Kb = Kh + (size_t)bh * S_ * DK_;
  const u16* Vb = Vt + (size_t)bh * DK_ * S_;

  // Q as QK^T B-operand: lane holds col q=l31, k-rows d = ds*16 + hi*8 + e
  bf16x8 qf[4];
#pragma unroll
  for (int ds = 0; ds < 4; ++ds)
    qf[ds] = ld16(Qb + (size_t)(q0 + l31) * DK_ + ds * 16 + hi * 8);

  f32x16 accO[2] = {};  // O^T: col q=l31, rows d=(r&3)+8*(r>>2)+4*hi + 32*dh
  float mreg = -1e30f, lsum = 0.f;
  const float SC = 0.125f * 1.44269504088896f;  // 1/sqrt(64) * log2(e)

  for (int kv = 0; kv < S_; kv += 64) {
    // ---- QK^T swapped: accS[t] = S^T[kk = t*32 + crow][q], crow=(r&3)+8*(r>>2)+4*hi
    f32x16 accS[2] = {};
#pragma unroll
    for (int t = 0; t < 2; ++t)
#pragma unroll
      for (int ds = 0; ds < 4; ++ds) {
        bf16x8 kf = ld16(Kb + (size_t)(kv + t * 32 + l31) * DK_ + ds * 16 + hi * 8);
        accS[t] = __builtin_amdgcn_mfma_f32_32x32x16_bf16(kf, qf[ds], accS[t], 0, 0, 0);
      }
    // ---- online softmax, fully lane-local (lane pair q / q+32 redundantly identical)
    float a[16];
#pragma unroll
    for (int r = 0; r < 16; ++r) a[r] = fmaxf(accS[0][r], accS[1][r]);
#pragma unroll
    for (int s = 8; s; s >>= 1)
#pragma unroll
      for (int r = 0; r < s; ++r) a[r] = fmaxf(a[r], a[r + s]);
    i32x2 mm = pl32swap(asi(a[0]), asi(a[0]));
    float mx = fmaxf(asf(mm.x), asf(mm.y));  // {own, partner} in some order
    float mnew = fmaxf(mreg, mx * SC);
    float scl = exp2f(mreg - mnew);
#pragma unroll
    for (int t = 0; t < 2; ++t)
#pragma unroll
      for (int r = 0; r < 16; ++r)
        accS[t][r] = exp2f(fmaf(accS[t][r], SC, -mnew));  // P in place
#pragma unroll
    for (int r = 0; r < 16; ++r) a[r] = accS[0][r] + accS[1][r];
#pragma unroll
    for (int s = 8; s; s >>= 1)
#pragma unroll
      for (int r = 0; r < s; ++r) a[r] += a[r + s];
    i32x2 ss = pl32swap(asi(a[0]), asi(a[0]));
    float rs = asf(ss.x) + asf(ss.y);
    lsum = lsum * scl + rs;
    mreg = mnew;
#pragma unroll
    for (int r = 0; r < 16; ++r) { accO[0][r] *= scl; accO[1][r] *= scl; }
    // ---- P^T -> PV B-frags via cvt_pk + permlane32_swap (T12)
    bf16x8 pb[4];
#pragma unroll
    for (int t = 0; t < 2; ++t) {
      i32x2 sA = pl32swap(cvtpk(accS[t][0], accS[t][1]), cvtpk(accS[t][4], accS[t][5]));
      i32x2 sB = pl32swap(cvtpk(accS[t][2], accS[t][3]), cvtpk(accS[t][6], accS[t][7]));
      i32x2 sC = pl32swap(cvtpk(accS[t][8], accS[t][9]), cvtpk(accS[t][12], accS[t][13]));
      i32x2 sD = pl32swap(cvtpk(accS[t][10], accS[t][11]), cvtpk(accS[t][14], accS[t][15]));
      union { i32x4 i; bf16x8 h; } u0, u1;
      u0.i = (i32x4){sA.x, sB.x, sA.y, sB.y};  // k-slot 2t:   lo k0..7,  hi k8..15
      u1.i = (i32x4){sC.x, sD.x, sC.y, sD.y};  // k-slot 2t+1: lo k16..23, hi k24..31
      pb[2 * t] = u0.h;
      pb[2 * t + 1] = u1.h;
    }
    // ---- PV swapped: accO[dh] += V^T(32d x 16k) * P^T(16k x 32q)
#pragma unroll
    for (int ks = 0; ks < 4; ++ks)
#pragma unroll
      for (int dh = 0; dh < 2; ++dh) {
        bf16x8 vf = ld16(Vb + (size_t)(dh * 32 + l31) * S_ + kv + ks * 16 + hi * 8);
        accO[dh] = __builtin_amdgcn_mfma_f32_32x32x16_bf16(vf, pb[ks], accO[dh], 0, 0, 0);
      }
  }
  // ---- epilogue: ctx[b][s=q0+l31][h*64+d], d = dh*32 + 8g + 4*hi + r
  const float inv = 1.f / lsum;
  const int b = bh >> 4, h = bh & 15;
  u16* crow = ctx + ((size_t)b * S_ + q0 + l31) * DM_ + h * DK_;
#pragma unroll
  for (int dh = 0; dh < 2; ++dh)
#pragma unroll
    for (int g = 0; g < 4; ++g) {
      u16x4 o;
#pragma unroll
      for (int r = 0; r < 4; ++r) o[r] = f2bf(accO[dh][g * 4 + r] * inv);
      *(u16x4*)(crow + dh * 32 + g * 8 + hi * 4) = o;
    }
}

// ---------------- launcher ----------------
// ws high-water: 4 weights (4x2.1MB) + 4 activation buffers (4x16.78MB) = 75.5 MB
extern "C" void kernel_launch(void* const* d_in, const int* in_sizes, int n_in,
                              void* d_out, int out_size, void* d_ws, size_t ws_size,
                              hipStream_t stream) {
  const float* q  = (const float*)d_in[0];
  const float* k  = (const float*)d_in[1];
  const float* v  = (const float*)d_in[2];
  const float* Wq = (const float*)d_in[3];
  const float* Wk = (const float*)d_in[4];
  const float* Wv = (const float*)d_in[5];
  const float* Wo = (const float*)d_in[6];

  char* ws = (char*)d_ws;
  const size_t SZX = (size_t)M_ * DM_ * 2;   // 16.78 MB bf16 activation
  const size_t SZW = (size_t)DM_ * DM_ * 2;  // 2.10 MB bf16 weight
  u16* Wqt = (u16*)(ws);
  u16* Wkt = (u16*)(ws + SZW);
  u16* Wvt = (u16*)(ws + 2 * SZW);
  u16* Wot = (u16*)(ws + 3 * SZW);
  u16* xb  = (u16*)(ws + 4 * SZW);            // q/k/v bf16 (sequential reuse), later ctx
  u16* Qh  = (u16*)(ws + 4 * SZW + SZX);
  u16* Kh  = (u16*)(ws + 4 * SZW + 2 * SZX);
  u16* Vt  = (u16*)(ws + 4 * SZW + 3 * SZX);
  u16* ctx = xb;  // xb free after V projection

  wtrans_kernel<<<dim3(16, 16), 256, 0, stream>>>(Wq, Wqt);
  wtrans_kernel<<<dim3(16, 16), 256, 0, stream>>>(Wk, Wkt);
  wtrans_kernel<<<dim3(16, 16), 256, 0, stream>>>(Wv, Wvt);
  wtrans_kernel<<<dim3(16, 16), 256, 0, stream>>>(Wo, Wot);

  cvt_kernel<<<8192, 256, 0, stream>>>(q, xb);
  gemm_bt<1><<<dim3(8, 64), 256, 0, stream>>>(xb, Wqt, Qh);
  cvt_kernel<<<8192, 256, 0, stream>>>(k, xb);
  gemm_bt<1><<<dim3(8, 64), 256, 0, stream>>>(xb, Wkt, Kh);
  cvt_kernel<<<8192, 256, 0, stream>>>(v, xb);
  gemm_bt<2><<<dim3(8, 64), 256, 0, stream>>>(xb, Wvt, Vt);

  attn_kernel<<<dim3(16, 64), 256, 0, stream>>>(Qh, Kh, Vt, ctx);
  gemm_bt<0><<<dim3(8, 64), 256, 0, stream>>>(ctx, Wot, d_out);
}

// Round 4
// 518.359 us; speedup vs baseline: 1.4161x; 1.1046x over previous
//
#include <hip/hip_runtime.h>
#include <hip/hip_bf16.h>

typedef unsigned short u16;
typedef __attribute__((ext_vector_type(8))) short bf16x8;   // 8 bf16 = 4 VGPRs (MFMA A/B operand)
typedef __attribute__((ext_vector_type(4))) float f32x4;    // 16x16 MFMA C/D
typedef __attribute__((ext_vector_type(16))) float f32x16;  // 32x32 MFMA C/D
typedef __attribute__((ext_vector_type(4))) u16 u16x4;
typedef __attribute__((ext_vector_type(2))) int i32x2;
typedef __attribute__((ext_vector_type(4))) int i32x4;

#define DEV __device__ __forceinline__

constexpr int B_ = 4, S_ = 2048, H_ = 16, DK_ = 64, DM_ = 1024;
constexpr int M_ = B_ * S_;  // 8192 rows for all GEMMs

DEV u16 f2bf(float x) {  // RNE fp32 -> bf16
  union { float f; unsigned u; } v; v.f = x;
  return (u16)((v.u + 0x7fffu + ((v.u >> 16) & 1u)) >> 16);
}

DEV bf16x8 ld16(const u16* p) { return *(const bf16x8*)p; }

DEV void g2l16(const void* g, void* l) {  // async global->LDS, 16B/lane, linear dest
  __builtin_amdgcn_global_load_lds((const __attribute__((address_space(1))) void*)g,
                                   (__attribute__((address_space(3))) void*)l, 16, 0, 0);
}

DEV int cvtpk(float lo, float hi) {  // packed bf16: [15:0]=bf16(lo), [31:16]=bf16(hi)
  int r;
  asm("v_cvt_pk_bf16_f32 %0, %1, %2" : "=v"(r) : "v"(lo), "v"(hi));
  return r;
}

DEV i32x2 pl32swap(int a, int b) {
  return __builtin_amdgcn_permlane32_swap(a, b, false, false);
}

DEV float asf(int x) { return __builtin_bit_cast(float, x); }
DEV int asi(float x) { return __builtin_bit_cast(int, x); }

// ---------------- fp32 -> bf16 convert (4 elems/thread, exact coverage) ----------------
__global__ __launch_bounds__(256) void cvt_kernel(const float* __restrict__ in,
                                                  u16* __restrict__ out) {
  int i = (blockIdx.x * 256 + threadIdx.x) * 4;
  float4 v = *(const float4*)(in + i);
  u16x4 o; o[0] = f2bf(v.x); o[1] = f2bf(v.y); o[2] = f2bf(v.z); o[3] = f2bf(v.w);
  *(u16x4*)(out + i) = o;
}

// ---------------- weight transpose-convert: W[K][N] fp32 -> Wt[N][K] bf16 ----------------
__global__ __launch_bounds__(256) void wtrans_kernel(const float* __restrict__ W,
                                                     u16* __restrict__ Wt) {
  __shared__ u16 t[64][68];
  const int r0 = blockIdx.y * 64, c0 = blockIdx.x * 64;
  const int lr = threadIdx.x >> 4;         // 0..15
  const int lc = (threadIdx.x & 15) * 4;   // 0..60
#pragma unroll
  for (int i = 0; i < 4; ++i) {
    int row = i * 16 + lr;
    float4 v = *(const float4*)(W + (size_t)(r0 + row) * DM_ + c0 + lc);
    t[lc + 0][row] = f2bf(v.x); t[lc + 1][row] = f2bf(v.y);
    t[lc + 2][row] = f2bf(v.z); t[lc + 3][row] = f2bf(v.w);
  }
  __syncthreads();
#pragma unroll
  for (int i = 0; i < 4; ++i) {
    int c = i * 16 + lr;
    u16x4 o; o[0] = t[c][lc]; o[1] = t[c][lc + 1]; o[2] = t[c][lc + 2]; o[3] = t[c][lc + 3];
    *(u16x4*)(Wt + (size_t)(c0 + c) * DM_ + r0 + lc) = o;
  }
}

// ---------------- GEMM: X[M][1024] bf16 x Wt[1024 n][1024 k] bf16 ----------------
// OUT_MODE 0: fp32 [M][1024] row-major (final out-proj)
// OUT_MODE 1: bf16 scattered to [b][h][s][d] (Q/K projections)
// OUT_MODE 2: bf16 scattered to [b][h][d][s] (V projection, pre-transposed for PV)
template <int OUT_MODE>
__global__ __launch_bounds__(256) void gemm_bt(const u16* __restrict__ X,
                                               const u16* __restrict__ Wt,
                                               void* __restrict__ outp) {
  constexpr int K = 1024, N = 1024;
  __shared__ u16 As[128 * 64];
  __shared__ u16 Bs[128 * 64];
  const int tid = threadIdx.x;
  const int w = tid >> 6, lane = tid & 63;
  const int l15 = lane & 15, lg = lane >> 4;
  const int m0 = blockIdx.y * 128, n0 = blockIdx.x * 128;
  const int wm = (w >> 1) * 64, wn = (w & 1) * 64;
  f32x4 acc[4][4] = {};

  const int srow = lane >> 3;        // row within 8-row LDS chunk
  const int scol = (lane & 7) * 8;   // k offset within tile

  for (int kt = 0; kt < K; kt += 64) {
#pragma unroll
    for (int i = 0; i < 4; ++i) {
      const int chunk = w * 4 + i;          // 16 chunks x 1KB cover the 16KB tile
      const int row = chunk * 8 + srow;
      g2l16(X + (size_t)(m0 + row) * K + kt + scol, As + chunk * 512);
      g2l16(Wt + (size_t)(n0 + row) * K + kt + scol, Bs + chunk * 512);
    }
    __syncthreads();
#pragma unroll
    for (int kk = 0; kk < 2; ++kk) {
      bf16x8 a[4], b[4];
#pragma unroll
      for (int i = 0; i < 4; ++i)
        a[i] = ld16(As + (wm + i * 16 + l15) * 64 + kk * 32 + lg * 8);
#pragma unroll
      for (int j = 0; j < 4; ++j)
        b[j] = ld16(Bs + (wn + j * 16 + l15) * 64 + kk * 32 + lg * 8);
#pragma unroll
      for (int i = 0; i < 4; ++i)
#pragma unroll
        for (int j = 0; j < 4; ++j)
          acc[i][j] = __builtin_amdgcn_mfma_f32_16x16x32_bf16(a[i], b[j], acc[i][j], 0, 0, 0);
    }
    __syncthreads();
  }
  // epilogue: C/D layout col=lane&15, row=(lane>>4)*4+r  [m89-verified]
#pragma unroll
  for (int i = 0; i < 4; ++i)
#pragma unroll
    for (int j = 0; j < 4; ++j) {
      if (OUT_MODE == 2) {
        // 4 consecutive s values per lane -> one 8B store into Vt[bh][d][s]
        int m = m0 + wm + i * 16 + lg * 4;   // s base (block rows never cross b)
        int n = n0 + wn + j * 16 + l15;
        int b = m >> 11, s = m & 2047;
        int h = n >> 6, d = n & 63;
        u16x4 o;
#pragma unroll
        for (int r = 0; r < 4; ++r) o[r] = f2bf(acc[i][j][r]);
        *(u16x4*)((u16*)outp + ((size_t)(b * H_ + h) * DK_ + d) * S_ + s) = o;
      } else {
#pragma unroll
        for (int r = 0; r < 4; ++r) {
          int m = m0 + wm + i * 16 + lg * 4 + r;
          int n = n0 + wn + j * 16 + l15;
          if (OUT_MODE == 0) {
            ((float*)outp)[(size_t)m * N + n] = acc[i][j][r];
          } else {
            int b = m >> 11, s = m & 2047;
            int h = n >> 6, d = n & 63;
            ((u16*)outp)[((size_t)(b * H_ + h) * S_ + s) * DK_ + d] = f2bf(acc[i][j][r]);
          }
        }
      }
    }
}

// ---------------- flash attention (swapped QK^T/PV + in-reg softmax + reg double-buffer) ----
// grid (S/128, B*H), 256 threads = 4 waves; each wave owns 32 q-rows. No LDS, no barriers.
// K/V frags for tile i+1 are loaded while tile i computes (T14); defer-max (T13); setprio (T5).
// Qh,Kh: [bh][S][64] bf16 ; Vt: [bh][64][S] bf16 ; ctx out: [b][s][h*64+d] bf16
__global__ __launch_bounds__(256, 2) void attn_kernel(const u16* __restrict__ Qh,
                                                      const u16* __restrict__ Kh,
                                                      const u16* __restrict__ Vt,
                                                      u16* __restrict__ ctx) {
  const int lane = threadIdx.x & 63, w = threadIdx.x >> 6;
  const int l31 = lane & 31, hi = lane >> 5;
  const int bh = blockIdx.y;
  const int q0 = blockIdx.x * 128 + w * 32;

  const u16* Qb = Qh + (size_t)bh * S_ * DK_;
  const u16* Kb = Kh + (size_t)bh * S_ * DK_;
  const u16* Vb = Vt + (size_t)bh * DK_ * S_;

  // Q as QK^T B-operand: lane holds col q=l31, k-rows d = ds*16 + hi*8 + e
  bf16x8 qf[4];
#pragma unroll
  for (int ds = 0; ds < 4; ++ds)
    qf[ds] = ld16(Qb + (size_t)(q0 + l31) * DK_ + ds * 16 + hi * 8);

  // per-lane fragment base addresses
  const u16* krow = Kb + (size_t)l31 * DK_ + hi * 8;      // + (kv + t*32)*DK_ + ds*16
  const u16* vrow0 = Vb + (size_t)l31 * S_ + hi * 8;      // + kv + ks*16
  const u16* vrow1 = Vb + (size_t)(32 + l31) * S_ + hi * 8;

  bf16x8 kc[8], vc[8], kn[8], vn[8];
#pragma unroll
  for (int t = 0; t < 2; ++t)
#pragma unroll
    for (int ds = 0; ds < 4; ++ds)
      kc[t * 4 + ds] = ld16(krow + (size_t)(t * 32) * DK_ + ds * 16);
#pragma unroll
  for (int ks = 0; ks < 4; ++ks) {
    vc[ks * 2 + 0] = ld16(vrow0 + ks * 16);
    vc[ks * 2 + 1] = ld16(vrow1 + ks * 16);
  }

  f32x16 accO[2] = {};  // O^T: col q=l31, rows d=(r&3)+8*(r>>2)+4*hi + 32*dh
  float mreg = -1e30f, lsum = 0.f;
  const float SC = 0.125f * 1.44269504088896f;  // 1/sqrt(64) * log2(e)

  for (int kv = 0; kv < S_; kv += 64) {
    // ---- prefetch next K/V tile into the alternate register set (wraps on last iter)
    const int nk = (kv + 64) & (S_ - 1);
#pragma unroll
    for (int t = 0; t < 2; ++t)
#pragma unroll
      for (int ds = 0; ds < 4; ++ds)
        kn[t * 4 + ds] = ld16(krow + (size_t)(nk + t * 32) * DK_ + ds * 16);
#pragma unroll
    for (int ks = 0; ks < 4; ++ks) {
      vn[ks * 2 + 0] = ld16(vrow0 + nk + ks * 16);
      vn[ks * 2 + 1] = ld16(vrow1 + nk + ks * 16);
    }

    // ---- QK^T swapped: accS[t] = S^T[kk = t*32 + crow][q], crow=(r&3)+8*(r>>2)+4*hi
    f32x16 accS[2] = {};
    __builtin_amdgcn_s_setprio(1);
#pragma unroll
    for (int ds = 0; ds < 4; ++ds) {
      accS[0] = __builtin_amdgcn_mfma_f32_32x32x16_bf16(kc[ds], qf[ds], accS[0], 0, 0, 0);
      accS[1] = __builtin_amdgcn_mfma_f32_32x32x16_bf16(kc[4 + ds], qf[ds], accS[1], 0, 0, 0);
    }
    __builtin_amdgcn_s_setprio(0);

    // ---- online softmax, lane-local; defer-max (T13, THR=8 in exp2 domain -> P<=256)
    float a[16];
#pragma unroll
    for (int r = 0; r < 16; ++r) a[r] = fmaxf(accS[0][r], accS[1][r]);
#pragma unroll
    for (int s = 8; s; s >>= 1)
#pragma unroll
      for (int r = 0; r < s; ++r) a[r] = fmaxf(a[r], a[r + s]);
    i32x2 mm = pl32swap(asi(a[0]), asi(a[0]));
    float mx = fmaxf(asf(mm.x), asf(mm.y)) * SC;
    if (__any(mx > mreg + 8.f)) {
      float mnew = fmaxf(mreg, mx);
      float scl = exp2f(mreg - mnew);
      mreg = mnew;
      lsum *= scl;
#pragma unroll
      for (int r = 0; r < 16; ++r) { accO[0][r] *= scl; accO[1][r] *= scl; }
    }
#pragma unroll
    for (int t = 0; t < 2; ++t)
#pragma unroll
      for (int r = 0; r < 16; ++r)
        accS[t][r] = exp2f(fmaf(accS[t][r], SC, -mreg));  // P in place
#pragma unroll
    for (int r = 0; r < 16; ++r) a[r] = accS[0][r] + accS[1][r];
#pragma unroll
    for (int s = 8; s; s >>= 1)
#pragma unroll
      for (int r = 0; r < s; ++r) a[r] += a[r + s];
    i32x2 ss = pl32swap(asi(a[0]), asi(a[0]));
    lsum += asf(ss.x) + asf(ss.y);

    // ---- P^T -> PV B-frags via cvt_pk + permlane32_swap (T12)
    bf16x8 pb[4];
#pragma unroll
    for (int t = 0; t < 2; ++t) {
      i32x2 sA = pl32swap(cvtpk(accS[t][0], accS[t][1]), cvtpk(accS[t][4], accS[t][5]));
      i32x2 sB = pl32swap(cvtpk(accS[t][2], accS[t][3]), cvtpk(accS[t][6], accS[t][7]));
      i32x2 sC = pl32swap(cvtpk(accS[t][8], accS[t][9]), cvtpk(accS[t][12], accS[t][13]));
      i32x2 sD = pl32swap(cvtpk(accS[t][10], accS[t][11]), cvtpk(accS[t][14], accS[t][15]));
      union { i32x4 i; bf16x8 h; } u0, u1;
      u0.i = (i32x4){sA.x, sB.x, sA.y, sB.y};  // k-slot 2t:   lo k0..7,  hi k8..15
      u1.i = (i32x4){sC.x, sD.x, sC.y, sD.y};  // k-slot 2t+1: lo k16..23, hi k24..31
      pb[2 * t] = u0.h;
      pb[2 * t + 1] = u1.h;
    }

    // ---- PV swapped: accO[dh] += V^T(32d x 16k) * P^T(16k x 32q)
    __builtin_amdgcn_s_setprio(1);
#pragma unroll
    for (int ks = 0; ks < 4; ++ks) {
      accO[0] = __builtin_amdgcn_mfma_f32_32x32x16_bf16(vc[ks * 2 + 0], pb[ks], accO[0], 0, 0, 0);
      accO[1] = __builtin_amdgcn_mfma_f32_32x32x16_bf16(vc[ks * 2 + 1], pb[ks], accO[1], 0, 0, 0);
    }
    __builtin_amdgcn_s_setprio(0);

    // ---- rotate double-buffer (SSA rename, no copies emitted)
#pragma unroll
    for (int f = 0; f < 8; ++f) { kc[f] = kn[f]; vc[f] = vn[f]; }
  }

  // ---- epilogue: ctx[b][s=q0+l31][h*64+d], d = dh*32 + 8g + 4*hi + r
  const float inv = 1.f / lsum;
  const int b = bh >> 4, h = bh & 15;
  u16* crow = ctx + ((size_t)b * S_ + q0 + l31) * DM_ + h * DK_;
#pragma unroll
  for (int dh = 0; dh < 2; ++dh)
#pragma unroll
    for (int g = 0; g < 4; ++g) {
      u16x4 o;
#pragma unroll
      for (int r = 0; r < 4; ++r) o[r] = f2bf(accO[dh][g * 4 + r] * inv);
      *(u16x4*)(crow + dh * 32 + g * 8 + hi * 4) = o;
    }
}

// ---------------- launcher ----------------
// ws high-water: 4 weights (4x2.1MB) + 4 activation buffers (4x16.78MB) = 75.5 MB
extern "C" void kernel_launch(void* const* d_in, const int* in_sizes, int n_in,
                              void* d_out, int out_size, void* d_ws, size_t ws_size,
                              hipStream_t stream) {
  const float* q  = (const float*)d_in[0];
  const float* k  = (const float*)d_in[1];
  const float* v  = (const float*)d_in[2];
  const float* Wq = (const float*)d_in[3];
  const float* Wk = (const float*)d_in[4];
  const float* Wv = (const float*)d_in[5];
  const float* Wo = (const float*)d_in[6];

  char* ws = (char*)d_ws;
  const size_t SZX = (size_t)M_ * DM_ * 2;   // 16.78 MB bf16 activation
  const size_t SZW = (size_t)DM_ * DM_ * 2;  // 2.10 MB bf16 weight
  u16* Wqt = (u16*)(ws);
  u16* Wkt = (u16*)(ws + SZW);
  u16* Wvt = (u16*)(ws + 2 * SZW);
  u16* Wot = (u16*)(ws + 3 * SZW);
  u16* xb  = (u16*)(ws + 4 * SZW);            // q/k/v bf16 (sequential reuse), later ctx
  u16* Qh  = (u16*)(ws + 4 * SZW + SZX);
  u16* Kh  = (u16*)(ws + 4 * SZW + 2 * SZX);
  u16* Vt  = (u16*)(ws + 4 * SZW + 3 * SZX);
  u16* ctx = xb;  // xb free after V projection

  wtrans_kernel<<<dim3(16, 16), 256, 0, stream>>>(Wq, Wqt);
  wtrans_kernel<<<dim3(16, 16), 256, 0, stream>>>(Wk, Wkt);
  wtrans_kernel<<<dim3(16, 16), 256, 0, stream>>>(Wv, Wvt);
  wtrans_kernel<<<dim3(16, 16), 256, 0, stream>>>(Wo, Wot);

  cvt_kernel<<<8192, 256, 0, stream>>>(q, xb);
  gemm_bt<1><<<dim3(8, 64), 256, 0, stream>>>(xb, Wqt, Qh);
  cvt_kernel<<<8192, 256, 0, stream>>>(k, xb);
  gemm_bt<1><<<dim3(8, 64), 256, 0, stream>>>(xb, Wkt, Kh);
  cvt_kernel<<<8192, 256, 0, stream>>>(v, xb);
  gemm_bt<2><<<dim3(8, 64), 256, 0, stream>>>(xb, Wvt, Vt);

  attn_kernel<<<dim3(16, 64), 256, 0, stream>>>(Qh, Kh, Vt, ctx);
  gemm_bt<0><<<dim3(8, 64), 256, 0, stream>>>(ctx, Wot, d_out);
}

// Round 5
// 510.006 us; speedup vs baseline: 1.4393x; 1.0164x over previous
//
#include <hip/hip_runtime.h>
#include <hip/hip_bf16.h>

typedef unsigned short u16;
typedef __attribute__((ext_vector_type(8))) short bf16x8;   // 8 bf16 = 4 VGPRs (MFMA A/B operand)
typedef __attribute__((ext_vector_type(4))) float f32x4;    // 16x16 MFMA C/D
typedef __attribute__((ext_vector_type(16))) float f32x16;  // 32x32 MFMA C/D
typedef __attribute__((ext_vector_type(4))) u16 u16x4;
typedef __attribute__((ext_vector_type(2))) int i32x2;
typedef __attribute__((ext_vector_type(4))) int i32x4;

#define DEV __device__ __forceinline__

constexpr int B_ = 4, S_ = 2048, H_ = 16, DK_ = 64, DM_ = 1024;
constexpr int M_ = B_ * S_;  // 8192 rows per GEMM

DEV u16 f2bf(float x) {  // RNE fp32 -> bf16
  union { float f; unsigned u; } v; v.f = x;
  return (u16)((v.u + 0x7fffu + ((v.u >> 16) & 1u)) >> 16);
}

DEV bf16x8 ld16(const u16* p) { return *(const bf16x8*)p; }

DEV void g2l16(const void* g, void* l) {  // async global->LDS, 16B/lane, linear dest
  __builtin_amdgcn_global_load_lds((const __attribute__((address_space(1))) void*)g,
                                   (__attribute__((address_space(3))) void*)l, 16, 0, 0);
}

DEV int cvtpk(float lo, float hi) {  // packed bf16 pair (RNE)
  int r;
  asm("v_cvt_pk_bf16_f32 %0, %1, %2" : "=v"(r) : "v"(lo), "v"(hi));
  return r;
}

DEV i32x2 pl32swap(int a, int b) {
  return __builtin_amdgcn_permlane32_swap(a, b, false, false);
}

DEV float asf(int x) { return __builtin_bit_cast(float, x); }
DEV int asi(float x) { return __builtin_bit_cast(int, x); }

// ---------------- weight transpose-convert: W[K][N] fp32 -> Wt[N][K] bf16 ----------------
__global__ __launch_bounds__(256) void wtrans_kernel(const float* __restrict__ W,
                                                     u16* __restrict__ Wt) {
  __shared__ u16 t[64][68];
  const int r0 = blockIdx.y * 64, c0 = blockIdx.x * 64;
  const int lr = threadIdx.x >> 4;
  const int lc = (threadIdx.x & 15) * 4;
#pragma unroll
  for (int i = 0; i < 4; ++i) {
    int row = i * 16 + lr;
    float4 v = *(const float4*)(W + (size_t)(r0 + row) * DM_ + c0 + lc);
    t[lc + 0][row] = f2bf(v.x); t[lc + 1][row] = f2bf(v.y);
    t[lc + 2][row] = f2bf(v.z); t[lc + 3][row] = f2bf(v.w);
  }
  __syncthreads();
#pragma unroll
  for (int i = 0; i < 4; ++i) {
    int c = i * 16 + lr;
    u16x4 o; o[0] = t[c][lc]; o[1] = t[c][lc + 1]; o[2] = t[c][lc + 2]; o[3] = t[c][lc + 3];
    *(u16x4*)(Wt + (size_t)(c0 + c) * DM_ + r0 + lc) = o;
  }
}

// ================= 256x256 GEMM, BK=64, 8 waves, lead-1 async double-buffer =================
// KIND 0: batched QKV. A = fp32 q/k/v (cvt fused into reg-staged A path). 384 blocks.
//         sel 0,1 -> bf16 scatter [b][h][s][d]; sel 2 -> bf16 scatter [b][h][d][s].
// KIND 1: out-proj. A = bf16 ctx via global_load_lds. 128 blocks. fp32 row-major out.
// LDS swizzle (T2): 16B chunk c4 stored at c4 ^ (row&7); applied on stage-src (B, DMA path),
// on ds_write dest (A fused-cvt path), and on every ds_read. Conflict-free b128 reads.
template <int KIND>
__global__ __launch_bounds__(512, 2) void gemm256(const float* __restrict__ x0f,
                                                  const float* __restrict__ x1f,
                                                  const float* __restrict__ x2f,
                                                  const u16* __restrict__ xb,
                                                  const u16* __restrict__ w0,
                                                  const u16* __restrict__ w1,
                                                  const u16* __restrict__ w2,
                                                  void* __restrict__ o0,
                                                  void* __restrict__ o1,
                                                  void* __restrict__ o2) {
  constexpr int K = 1024, NK = 16;  // 16 K-tiles of 64
  __shared__ u16 As[2][16384];      // [slot][256 rows][64 cols] bf16, 32KB/slot
  __shared__ u16 Bs[2][16384];
  const int tid = threadIdx.x;
  const int w = tid >> 6, lane = tid & 63;
  const int l15 = lane & 15, lg = (lane >> 4) & 3;
  const int ln8 = lane >> 3, c8 = (lane & 7);
  const int cg = c8 ^ ln8;  // stage chunk swizzle: row&7 == ln8 for all staged rows

  // ---- bijective XCD swizzle (gridDim.x % 8 == 0 for both KINDs)
  const int wg = blockIdx.x;
  const int cpx = gridDim.x >> 3;
  const int idx = (wg & 7) * cpx + (wg >> 3);
  const int nblk = idx & 3, mblk = idx >> 2;
  const int sel = (KIND == 0) ? (mblk >> 5) : 0;
  const int m0 = (KIND == 0) ? (mblk & 31) * 256 : mblk * 256;
  const int n0 = nblk * 256;

  const float* Xf = nullptr;
  const u16* Wt;
  if (KIND == 0) {
    Xf = sel == 0 ? x0f : sel == 1 ? x1f : x2f;
    Wt = sel == 0 ? w0 : sel == 1 ? w1 : w2;
  } else {
    Wt = w0;
  }

  // wave tiling: 2M x 4N waves, each 128x64 output = 8x4 frags of 16x16
  const int wm = (w >> 2) * 128, wn = (w & 3) * 64;
  f32x4 acc[8][4] = {};

  // staged-row base for this thread (per h,l): r = h*128 + l*64 + w*8 + ln8
  // prologue: stage K-tile 0 -> slot 0
  {
#pragma unroll
    for (int h = 0; h < 2; ++h)
#pragma unroll
      for (int l = 0; l < 2; ++l) {
        int r = h * 128 + l * 64 + w * 8 + ln8;
        g2l16(Wt + (size_t)(n0 + r) * K + cg * 8, &Bs[0][h * 8192 + (l * 512 + w * 64) * 8]);
      }
    if (KIND == 0) {
#pragma unroll
      for (int h = 0; h < 2; ++h)
#pragma unroll
        for (int l = 0; l < 2; ++l) {
          int r = h * 128 + l * 64 + w * 8 + ln8;
          const float* src = Xf + (size_t)(m0 + r) * K + c8 * 8;
          float4 u = *(const float4*)src, v2 = *(const float4*)(src + 4);
          i32x4 pk = {cvtpk(u.x, u.y), cvtpk(u.z, u.w), cvtpk(v2.x, v2.y), cvtpk(v2.z, v2.w)};
          *(i32x4*)(&As[0][r * 64 + cg * 8]) = pk;
        }
    } else {
#pragma unroll
      for (int h = 0; h < 2; ++h)
#pragma unroll
        for (int l = 0; l < 2; ++l) {
          int r = h * 128 + l * 64 + w * 8 + ln8;
          g2l16(xb + (size_t)(m0 + r) * K + cg * 8, &As[0][h * 8192 + (l * 512 + w * 64) * 8]);
        }
    }
  }

  for (int g = 0; g < NK; ++g) {
    // ---- group boundary: K-tile g landed (issued a full group ago), prior reads/writes done
    asm volatile("s_waitcnt vmcnt(0) lgkmcnt(0)" ::: "memory");
    __builtin_amdgcn_s_barrier();
    asm volatile("" ::: "memory");
    const int rs = g & 1, ws2 = (g + 1) & 1;
    const bool st = (g + 1) < NK;
    const int kt1 = (g + 1) * 64;

    // ---- issue next-tile staging (lands in the idle slot; waited at next boundary)
    float4 au[4], av[4];
    if (st) {
#pragma unroll
      for (int h = 0; h < 2; ++h)
#pragma unroll
        for (int l = 0; l < 2; ++l) {
          int r = h * 128 + l * 64 + w * 8 + ln8;
          g2l16(Wt + (size_t)(n0 + r) * K + kt1 + cg * 8,
                &Bs[ws2][h * 8192 + (l * 512 + w * 64) * 8]);
        }
      if (KIND == 0) {
#pragma unroll
        for (int h = 0; h < 2; ++h)
#pragma unroll
          for (int l = 0; l < 2; ++l) {
            int r = h * 128 + l * 64 + w * 8 + ln8;
            const float* src = Xf + (size_t)(m0 + r) * K + kt1 + c8 * 8;
            au[h * 2 + l] = *(const float4*)src;
            av[h * 2 + l] = *(const float4*)(src + 4);
          }
      } else {
#pragma unroll
        for (int h = 0; h < 2; ++h)
#pragma unroll
          for (int l = 0; l < 2; ++l) {
            int r = h * 128 + l * 64 + w * 8 + ln8;
            g2l16(xb + (size_t)(m0 + r) * K + kt1 + cg * 8,
                  &As[ws2][h * 8192 + (l * 512 + w * 64) * 8]);
          }
      }
    }

    // ---- compute: 2 k-slots x 32 MFMA, swizzled conflict-free ds_read_b128
#pragma unroll
    for (int kk = 0; kk < 2; ++kk) {
      bf16x8 af[8], bfr[4];
      const int ck = (kk * 4 + lg) ^ (l15 & 7);
#pragma unroll
      for (int mf = 0; mf < 8; ++mf)
        af[mf] = ld16(&As[rs][(wm + mf * 16 + l15) * 64 + ck * 8]);
#pragma unroll
      for (int nf = 0; nf < 4; ++nf)
        bfr[nf] = ld16(&Bs[rs][(wn + nf * 16 + l15) * 64 + ck * 8]);
      __builtin_amdgcn_s_setprio(1);
#pragma unroll
      for (int mf = 0; mf < 8; ++mf)
#pragma unroll
        for (int nf = 0; nf < 4; ++nf)
          acc[mf][nf] = __builtin_amdgcn_mfma_f32_16x16x32_bf16(af[mf], bfr[nf], acc[mf][nf], 0, 0, 0);
      __builtin_amdgcn_s_setprio(0);
    }

    // ---- deferred A-write (T14: loads issued at top, written after compute)
    if (KIND == 0 && st) {
      __builtin_amdgcn_sched_barrier(0);
#pragma unroll
      for (int h = 0; h < 2; ++h)
#pragma unroll
        for (int l = 0; l < 2; ++l) {
          int r = h * 128 + l * 64 + w * 8 + ln8;
          float4 u = au[h * 2 + l], v2 = av[h * 2 + l];
          i32x4 pk = {cvtpk(u.x, u.y), cvtpk(u.z, u.w), cvtpk(v2.x, v2.y), cvtpk(v2.z, v2.w)};
          *(i32x4*)(&As[ws2][r * 64 + cg * 8]) = pk;
        }
    }
  }

  // ---- epilogue: C/D layout col=lane&15, row=(lane>>4)*4+r  [m89-verified]
#pragma unroll
  for (int mf = 0; mf < 8; ++mf)
#pragma unroll
    for (int nf = 0; nf < 4; ++nf) {
      if (KIND == 0 && sel == 2) {
        int m = m0 + wm + mf * 16 + lg * 4;
        int n = n0 + wn + nf * 16 + l15;
        int b = m >> 11, s = m & 2047;
        int h = n >> 6, d = n & 63;
        u16x4 o;
#pragma unroll
        for (int r = 0; r < 4; ++r) o[r] = f2bf(acc[mf][nf][r]);
        *(u16x4*)((u16*)o2 + ((size_t)(b * H_ + h) * DK_ + d) * S_ + s) = o;
      } else if (KIND == 0) {
        u16* op = (u16*)(sel == 0 ? o0 : o1);
#pragma unroll
        for (int r = 0; r < 4; ++r) {
          int m = m0 + wm + mf * 16 + lg * 4 + r;
          int n = n0 + wn + nf * 16 + l15;
          int b = m >> 11, s = m & 2047;
          int h = n >> 6, d = n & 63;
          op[((size_t)(b * H_ + h) * S_ + s) * DK_ + d] = f2bf(acc[mf][nf][r]);
        }
      } else {
#pragma unroll
        for (int r = 0; r < 4; ++r) {
          int m = m0 + wm + mf * 16 + lg * 4 + r;
          int n = n0 + wn + nf * 16 + l15;
          ((float*)o0)[(size_t)m * DM_ + n] = acc[mf][nf][r];
        }
      }
    }
}

// ---------------- flash attention (swapped QK^T/PV + in-reg softmax + reg double-buffer) ----
__global__ __launch_bounds__(256, 2) void attn_kernel(const u16* __restrict__ Qh,
                                                      const u16* __restrict__ Kh,
                                                      const u16* __restrict__ Vt,
                                                      u16* __restrict__ ctx) {
  const int lane = threadIdx.x & 63, w = threadIdx.x >> 6;
  const int l31 = lane & 31, hi = lane >> 5;
  const int bh = blockIdx.y;
  const int q0 = blockIdx.x * 128 + w * 32;

  const u16* Qb = Qh + (size_t)bh * S_ * DK_;
  const u16* Kb = Kh + (size_t)bh * S_ * DK_;
  const u16* Vb = Vt + (size_t)bh * DK_ * S_;

  bf16x8 qf[4];
#pragma unroll
  for (int ds = 0; ds < 4; ++ds)
    qf[ds] = ld16(Qb + (size_t)(q0 + l31) * DK_ + ds * 16 + hi * 8);

  const u16* krow = Kb + (size_t)l31 * DK_ + hi * 8;
  const u16* vrow0 = Vb + (size_t)l31 * S_ + hi * 8;
  const u16* vrow1 = Vb + (size_t)(32 + l31) * S_ + hi * 8;

  bf16x8 kc[8], vc[8], kn[8], vn[8];
#pragma unroll
  for (int t = 0; t < 2; ++t)
#pragma unroll
    for (int ds = 0; ds < 4; ++ds)
      kc[t * 4 + ds] = ld16(krow + (size_t)(t * 32) * DK_ + ds * 16);
#pragma unroll
  for (int ks = 0; ks < 4; ++ks) {
    vc[ks * 2 + 0] = ld16(vrow0 + ks * 16);
    vc[ks * 2 + 1] = ld16(vrow1 + ks * 16);
  }

  f32x16 accO[2] = {};
  float mreg = -1e30f, lsum = 0.f;
  const float SC = 0.125f * 1.44269504088896f;

  for (int kv = 0; kv < S_; kv += 64) {
    const int nk = (kv + 64) & (S_ - 1);
#pragma unroll
    for (int t = 0; t < 2; ++t)
#pragma unroll
      for (int ds = 0; ds < 4; ++ds)
        kn[t * 4 + ds] = ld16(krow + (size_t)(nk + t * 32) * DK_ + ds * 16);
#pragma unroll
    for (int ks = 0; ks < 4; ++ks) {
      vn[ks * 2 + 0] = ld16(vrow0 + nk + ks * 16);
      vn[ks * 2 + 1] = ld16(vrow1 + nk + ks * 16);
    }

    f32x16 accS[2] = {};
    __builtin_amdgcn_s_setprio(1);
#pragma unroll
    for (int ds = 0; ds < 4; ++ds) {
      accS[0] = __builtin_amdgcn_mfma_f32_32x32x16_bf16(kc[ds], qf[ds], accS[0], 0, 0, 0);
      accS[1] = __builtin_amdgcn_mfma_f32_32x32x16_bf16(kc[4 + ds], qf[ds], accS[1], 0, 0, 0);
    }
    __builtin_amdgcn_s_setprio(0);

    float a[16];
#pragma unroll
    for (int r = 0; r < 16; ++r) a[r] = fmaxf(accS[0][r], accS[1][r]);
#pragma unroll
    for (int s = 8; s; s >>= 1)
#pragma unroll
      for (int r = 0; r < s; ++r) a[r] = fmaxf(a[r], a[r + s]);
    i32x2 mm = pl32swap(asi(a[0]), asi(a[0]));
    float mx = fmaxf(asf(mm.x), asf(mm.y)) * SC;
    if (__any(mx > mreg + 8.f)) {
      float mnew = fmaxf(mreg, mx);
      float scl = exp2f(mreg - mnew);
      mreg = mnew;
      lsum *= scl;
#pragma unroll
      for (int r = 0; r < 16; ++r) { accO[0][r] *= scl; accO[1][r] *= scl; }
    }
#pragma unroll
    for (int t = 0; t < 2; ++t)
#pragma unroll
      for (int r = 0; r < 16; ++r)
        accS[t][r] = exp2f(fmaf(accS[t][r], SC, -mreg));
#pragma unroll
    for (int r = 0; r < 16; ++r) a[r] = accS[0][r] + accS[1][r];
#pragma unroll
    for (int s = 8; s; s >>= 1)
#pragma unroll
      for (int r = 0; r < s; ++r) a[r] += a[r + s];
    i32x2 ss = pl32swap(asi(a[0]), asi(a[0]));
    lsum += asf(ss.x) + asf(ss.y);

    bf16x8 pb[4];
#pragma unroll
    for (int t = 0; t < 2; ++t) {
      i32x2 sA = pl32swap(cvtpk(accS[t][0], accS[t][1]), cvtpk(accS[t][4], accS[t][5]));
      i32x2 sB = pl32swap(cvtpk(accS[t][2], accS[t][3]), cvtpk(accS[t][6], accS[t][7]));
      i32x2 sC = pl32swap(cvtpk(accS[t][8], accS[t][9]), cvtpk(accS[t][12], accS[t][13]));
      i32x2 sD = pl32swap(cvtpk(accS[t][10], accS[t][11]), cvtpk(accS[t][14], accS[t][15]));
      union { i32x4 i; bf16x8 h; } u0, u1;
      u0.i = (i32x4){sA.x, sB.x, sA.y, sB.y};
      u1.i = (i32x4){sC.x, sD.x, sC.y, sD.y};
      pb[2 * t] = u0.h;
      pb[2 * t + 1] = u1.h;
    }

    __builtin_amdgcn_s_setprio(1);
#pragma unroll
    for (int ks = 0; ks < 4; ++ks) {
      accO[0] = __builtin_amdgcn_mfma_f32_32x32x16_bf16(vc[ks * 2 + 0], pb[ks], accO[0], 0, 0, 0);
      accO[1] = __builtin_amdgcn_mfma_f32_32x32x16_bf16(vc[ks * 2 + 1], pb[ks], accO[1], 0, 0, 0);
    }
    __builtin_amdgcn_s_setprio(0);

#pragma unroll
    for (int f = 0; f < 8; ++f) { kc[f] = kn[f]; vc[f] = vn[f]; }
  }

  const float inv = 1.f / lsum;
  const int b = bh >> 4, h = bh & 15;
  u16* crow = ctx + ((size_t)b * S_ + q0 + l31) * DM_ + h * DK_;
#pragma unroll
  for (int dh = 0; dh < 2; ++dh)
#pragma unroll
    for (int g = 0; g < 4; ++g) {
      u16x4 o;
#pragma unroll
      for (int r = 0; r < 4; ++r) o[r] = f2bf(accO[dh][g * 4 + r] * inv);
      *(u16x4*)(crow + dh * 32 + g * 8 + hi * 4) = o;
    }
}

// ---------------- launcher ----------------
// ws high-water: 4 weights (4x2.1MB) + Qh/Kh/Vt (3x16.8) + ctx (16.8) = 75.5 MB
extern "C" void kernel_launch(void* const* d_in, const int* in_sizes, int n_in,
                              void* d_out, int out_size, void* d_ws, size_t ws_size,
                              hipStream_t stream) {
  const float* q  = (const float*)d_in[0];
  const float* k  = (const float*)d_in[1];
  const float* v  = (const float*)d_in[2];
  const float* Wq = (const float*)d_in[3];
  const float* Wk = (const float*)d_in[4];
  const float* Wv = (const float*)d_in[5];
  const float* Wo = (const float*)d_in[6];

  char* ws = (char*)d_ws;
  const size_t SZX = (size_t)M_ * DM_ * 2;   // 16.78 MB bf16 activation
  const size_t SZW = (size_t)DM_ * DM_ * 2;  // 2.10 MB bf16 weight
  u16* Wqt = (u16*)(ws);
  u16* Wkt = (u16*)(ws + SZW);
  u16* Wvt = (u16*)(ws + 2 * SZW);
  u16* Wot = (u16*)(ws + 3 * SZW);
  u16* Qh  = (u16*)(ws + 4 * SZW);
  u16* Kh  = (u16*)(ws + 4 * SZW + SZX);
  u16* Vt  = (u16*)(ws + 4 * SZW + 2 * SZX);
  u16* ctx = (u16*)(ws + 4 * SZW + 3 * SZX);

  wtrans_kernel<<<dim3(16, 16), 256, 0, stream>>>(Wq, Wqt);
  wtrans_kernel<<<dim3(16, 16), 256, 0, stream>>>(Wk, Wkt);
  wtrans_kernel<<<dim3(16, 16), 256, 0, stream>>>(Wv, Wvt);
  wtrans_kernel<<<dim3(16, 16), 256, 0, stream>>>(Wo, Wot);

  // batched QKV: 96 m-blocks (32 per input) x 4 n-blocks = 384 blocks
  gemm256<0><<<dim3(384), 512, 0, stream>>>(q, k, v, nullptr, Wqt, Wkt, Wvt, Qh, Kh, Vt);

  attn_kernel<<<dim3(16, 64), 256, 0, stream>>>(Qh, Kh, Vt, ctx);

  // out-proj: 32 m-blocks x 4 n-blocks = 128 blocks
  gemm256<1><<<dim3(128), 512, 0, stream>>>(nullptr, nullptr, nullptr, ctx,
                                            Wot, nullptr, nullptr, d_out, nullptr, nullptr);
}

// Round 8
// 384.760 us; speedup vs baseline: 1.9078x; 1.3255x over previous
//
#include <hip/hip_runtime.h>
#include <hip/hip_bf16.h>

typedef unsigned short u16;
typedef __attribute__((ext_vector_type(8))) short bf16x8;   // 8 bf16 = 4 VGPRs (MFMA A/B operand)
typedef __attribute__((ext_vector_type(4))) float f32x4;    // 16x16 MFMA C/D
typedef __attribute__((ext_vector_type(16))) float f32x16;  // 32x32 MFMA C/D
typedef __attribute__((ext_vector_type(4))) u16 u16x4;
typedef __attribute__((ext_vector_type(2))) int i32x2;
typedef __attribute__((ext_vector_type(4))) int i32x4;

#define DEV __device__ __forceinline__

constexpr int B_ = 4, S_ = 2048, H_ = 16, DK_ = 64, DM_ = 1024;
constexpr int M_ = B_ * S_;  // 8192 rows per GEMM

DEV u16 f2bf(float x) {  // RNE fp32 -> bf16
  union { float f; unsigned u; } v; v.f = x;
  return (u16)((v.u + 0x7fffu + ((v.u >> 16) & 1u)) >> 16);
}

DEV bf16x8 ld16(const u16* p) { return *(const bf16x8*)p; }

DEV void g2l16(const void* g, void* l) {  // async global->LDS, 16B/lane, wave-uniform dest
  __builtin_amdgcn_global_load_lds((const __attribute__((address_space(1))) void*)g,
                                   (__attribute__((address_space(3))) void*)l, 16, 0, 0);
}

DEV int cvtpk(float lo, float hi) {  // packed bf16 pair (RNE)
  int r;
  asm("v_cvt_pk_bf16_f32 %0, %1, %2" : "=v"(r) : "v"(lo), "v"(hi));
  return r;
}

DEV i32x2 pl32swap(int a, int b) {
  return __builtin_amdgcn_permlane32_swap(a, b, false, false);
}

DEV float asf(int x) { return __builtin_bit_cast(float, x); }
DEV int asi(float x) { return __builtin_bit_cast(int, x); }

// ---------------- weight transpose-convert: W[K][N] fp32 -> Wt[N][K] bf16 ----------------
__global__ __launch_bounds__(256) void wtrans_kernel(const float* __restrict__ W,
                                                     u16* __restrict__ Wt) {
  __shared__ u16 t[64][68];
  const int r0 = blockIdx.y * 64, c0 = blockIdx.x * 64;
  const int lr = threadIdx.x >> 4;
  const int lc = (threadIdx.x & 15) * 4;
#pragma unroll
  for (int i = 0; i < 4; ++i) {
    int row = i * 16 + lr;
    float4 v = *(const float4*)(W + (size_t)(r0 + row) * DM_ + c0 + lc);
    t[lc + 0][row] = f2bf(v.x); t[lc + 1][row] = f2bf(v.y);
    t[lc + 2][row] = f2bf(v.z); t[lc + 3][row] = f2bf(v.w);
  }
  __syncthreads();
#pragma unroll
  for (int i = 0; i < 4; ++i) {
    int c = i * 16 + lr;
    u16x4 o; o[0] = t[c][lc]; o[1] = t[c][lc + 1]; o[2] = t[c][lc + 2]; o[3] = t[c][lc + 3];
    *(u16x4*)(Wt + (size_t)(c0 + c) * DM_ + r0 + lc) = o;
  }
}

// ================= 256x256 GEMM, BK=64, 8 waves, lead-1 async double-buffer =================
// (unchanged from round 5 — known-correct baseline; 8-phase port is the next structural step)
template <int KIND>
__global__ __launch_bounds__(512, 2) void gemm256(const float* __restrict__ x0f,
                                                  const float* __restrict__ x1f,
                                                  const float* __restrict__ x2f,
                                                  const u16* __restrict__ xb,
                                                  const u16* __restrict__ w0,
                                                  const u16* __restrict__ w1,
                                                  const u16* __restrict__ w2,
                                                  void* __restrict__ o0,
                                                  void* __restrict__ o1,
                                                  void* __restrict__ o2) {
  constexpr int K = 1024, NK = 16;  // 16 K-tiles of 64
  __shared__ u16 As[2][16384];      // [slot][256 rows][64 cols] bf16, 32KB/slot
  __shared__ u16 Bs[2][16384];
  const int tid = threadIdx.x;
  const int w = tid >> 6, lane = tid & 63;
  const int l15 = lane & 15, lg = (lane >> 4) & 3;
  const int ln8 = lane >> 3, c8 = (lane & 7);
  const int cg = c8 ^ ln8;  // stage chunk swizzle: row&7 == ln8 for all staged rows

  const int wg = blockIdx.x;
  const int cpx = gridDim.x >> 3;
  const int idx = (wg & 7) * cpx + (wg >> 3);
  const int nblk = idx & 3, mblk = idx >> 2;
  const int sel = (KIND == 0) ? (mblk >> 5) : 0;
  const int m0 = (KIND == 0) ? (mblk & 31) * 256 : mblk * 256;
  const int n0 = nblk * 256;

  const float* Xf = nullptr;
  const u16* Wt;
  if (KIND == 0) {
    Xf = sel == 0 ? x0f : sel == 1 ? x1f : x2f;
    Wt = sel == 0 ? w0 : sel == 1 ? w1 : w2;
  } else {
    Wt = w0;
  }

  const int wm = (w >> 2) * 128, wn = (w & 3) * 64;
  f32x4 acc[8][4] = {};

  {
#pragma unroll
    for (int h = 0; h < 2; ++h)
#pragma unroll
      for (int l = 0; l < 2; ++l) {
        int r = h * 128 + l * 64 + w * 8 + ln8;
        g2l16(Wt + (size_t)(n0 + r) * K + cg * 8, &Bs[0][h * 8192 + (l * 512 + w * 64) * 8]);
      }
    if (KIND == 0) {
#pragma unroll
      for (int h = 0; h < 2; ++h)
#pragma unroll
        for (int l = 0; l < 2; ++l) {
          int r = h * 128 + l * 64 + w * 8 + ln8;
          const float* src = Xf + (size_t)(m0 + r) * K + c8 * 8;
          float4 u = *(const float4*)src, v2 = *(const float4*)(src + 4);
          i32x4 pk = {cvtpk(u.x, u.y), cvtpk(u.z, u.w), cvtpk(v2.x, v2.y), cvtpk(v2.z, v2.w)};
          *(i32x4*)(&As[0][r * 64 + cg * 8]) = pk;
        }
    } else {
#pragma unroll
      for (int h = 0; h < 2; ++h)
#pragma unroll
        for (int l = 0; l < 2; ++l) {
          int r = h * 128 + l * 64 + w * 8 + ln8;
          g2l16(xb + (size_t)(m0 + r) * K + cg * 8, &As[0][h * 8192 + (l * 512 + w * 64) * 8]);
        }
    }
  }

  for (int g = 0; g < NK; ++g) {
    asm volatile("s_waitcnt vmcnt(0) lgkmcnt(0)" ::: "memory");
    __builtin_amdgcn_s_barrier();
    asm volatile("" ::: "memory");
    const int rs = g & 1, ws2 = (g + 1) & 1;
    const bool st = (g + 1) < NK;
    const int kt1 = (g + 1) * 64;

    float4 au[4], av[4];
    if (st) {
#pragma unroll
      for (int h = 0; h < 2; ++h)
#pragma unroll
        for (int l = 0; l < 2; ++l) {
          int r = h * 128 + l * 64 + w * 8 + ln8;
          g2l16(Wt + (size_t)(n0 + r) * K + kt1 + cg * 8,
                &Bs[ws2][h * 8192 + (l * 512 + w * 64) * 8]);
        }
      if (KIND == 0) {
#pragma unroll
        for (int h = 0; h < 2; ++h)
#pragma unroll
          for (int l = 0; l < 2; ++l) {
            int r = h * 128 + l * 64 + w * 8 + ln8;
            const float* src = Xf + (size_t)(m0 + r) * K + kt1 + c8 * 8;
            au[h * 2 + l] = *(const float4*)src;
            av[h * 2 + l] = *(const float4*)(src + 4);
          }
      } else {
#pragma unroll
        for (int h = 0; h < 2; ++h)
#pragma unroll
          for (int l = 0; l < 2; ++l) {
            int r = h * 128 + l * 64 + w * 8 + ln8;
            g2l16(xb + (size_t)(m0 + r) * K + kt1 + cg * 8,
                  &As[ws2][h * 8192 + (l * 512 + w * 64) * 8]);
          }
      }
    }

#pragma unroll
    for (int kk = 0; kk < 2; ++kk) {
      bf16x8 af[8], bfr[4];
      const int ck = (kk * 4 + lg) ^ (l15 & 7);
#pragma unroll
      for (int mf = 0; mf < 8; ++mf)
        af[mf] = ld16(&As[rs][(wm + mf * 16 + l15) * 64 + ck * 8]);
#pragma unroll
      for (int nf = 0; nf < 4; ++nf)
        bfr[nf] = ld16(&Bs[rs][(wn + nf * 16 + l15) * 64 + ck * 8]);
      __builtin_amdgcn_s_setprio(1);
#pragma unroll
      for (int mf = 0; mf < 8; ++mf)
#pragma unroll
        for (int nf = 0; nf < 4; ++nf)
          acc[mf][nf] = __builtin_amdgcn_mfma_f32_16x16x32_bf16(af[mf], bfr[nf], acc[mf][nf], 0, 0, 0);
      __builtin_amdgcn_s_setprio(0);
    }

    if (KIND == 0 && st) {
      __builtin_amdgcn_sched_barrier(0);
#pragma unroll
      for (int h = 0; h < 2; ++h)
#pragma unroll
        for (int l = 0; l < 2; ++l) {
          int r = h * 128 + l * 64 + w * 8 + ln8;
          float4 u = au[h * 2 + l], v2 = av[h * 2 + l];
          i32x4 pk = {cvtpk(u.x, u.y), cvtpk(u.z, u.w), cvtpk(v2.x, v2.y), cvtpk(v2.z, v2.w)};
          *(i32x4*)(&As[ws2][r * 64 + cg * 8]) = pk;
        }
    }
  }

#pragma unroll
  for (int mf = 0; mf < 8; ++mf)
#pragma unroll
    for (int nf = 0; nf < 4; ++nf) {
      if (KIND == 0 && sel == 2) {
        int m = m0 + wm + mf * 16 + lg * 4;
        int n = n0 + wn + nf * 16 + l15;
        int b = m >> 11, s = m & 2047;
        int h = n >> 6, d = n & 63;
        u16x4 o;
#pragma unroll
        for (int r = 0; r < 4; ++r) o[r] = f2bf(acc[mf][nf][r]);
        *(u16x4*)((u16*)o2 + ((size_t)(b * H_ + h) * DK_ + d) * S_ + s) = o;
      } else if (KIND == 0) {
        u16* op = (u16*)(sel == 0 ? o0 : o1);
#pragma unroll
        for (int r = 0; r < 4; ++r) {
          int m = m0 + wm + mf * 16 + lg * 4 + r;
          int n = n0 + wn + nf * 16 + l15;
          int b = m >> 11, s = m & 2047;
          int h = n >> 6, d = n & 63;
          op[((size_t)(b * H_ + h) * S_ + s) * DK_ + d] = f2bf(acc[mf][nf][r]);
        }
      } else {
#pragma unroll
        for (int r = 0; r < 4; ++r) {
          int m = m0 + wm + mf * 16 + lg * 4 + r;
          int n = n0 + wn + nf * 16 + l15;
          ((float*)o0)[(size_t)m * DM_ + n] = acc[mf][nf][r];
        }
      }
    }
}

// ---------------- flash attention: LDS-staged K/V (lead-1 dbuf) + in-reg softmax ----------
// grid (S/128, B*H), 256 threads = 4 waves; waves SHARE the staged K/V tile.
// Per iter: syncthreads (drains prev DMA, issued a full phase ago) -> issue next-tile DMA
// -> compute from LDS. Swizzle: linear DMA dest + inverse-swizzled SOURCE chunk (m201).
__global__ __launch_bounds__(256, 4) void attn_kernel(const u16* __restrict__ Qh,
                                                      const u16* __restrict__ Kh,
                                                      const u16* __restrict__ Vt,
                                                      u16* __restrict__ ctx) {
  __shared__ u16 KV[2][2][4096];  // [slot][K/V][64 rows x 64 cols], 32 KB
  const int tid = threadIdx.x;
  const int lane = tid & 63, w = tid >> 6;
  const int l31 = lane & 31, hi = lane >> 5;
  const int bh = blockIdx.y;
  const int q0 = blockIdx.x * 128 + w * 32;

  const u16* Qb = Qh + (size_t)bh * S_ * DK_;
  const u16* Kb = Kh + (size_t)bh * S_ * DK_;
  const u16* Vb = Vt + (size_t)bh * DK_ * S_;

  // staging geometry: thread covers rows j*32 + (tid>>3), dest chunk tid&7 (linear),
  // source chunk cs = (tid&7) ^ (row&7)  [involution; readers XOR the same mask]
  const int srow = tid >> 3;
  const int cs = (tid & 7) ^ (srow & 7);
  const int dstoff = w * 512;  // u16 units; wave-uniform dest base (+lane*16B by HW)

  // Q as QK^T B-operand: lane holds col q=l31, k-rows d = ds*16 + hi*8 + e
  bf16x8 qf[4];
#pragma unroll
  for (int ds = 0; ds < 4; ++ds)
    qf[ds] = ld16(Qb + (size_t)(q0 + l31) * DK_ + ds * 16 + hi * 8);

  f32x16 accO[2] = {};  // O^T: col q=l31, rows d=(r&3)+8*(r>>2)+4*hi + 32*dh
  float mreg = -1e30f, lsum = 0.f;
  const float SC = 0.125f * 1.44269504088896f;  // 1/sqrt(64) * log2(e)
  const int swz = (l31 & 7);  // read-side XOR mask (row&7 == l31&7 for all tiles)

  // prologue: stage tile 0 -> slot 0
#pragma unroll
  for (int j = 0; j < 2; ++j) {
    int r = j * 32 + srow;
    g2l16(Kb + (size_t)r * DK_ + cs * 8, &KV[0][0][j * 2048 + dstoff]);
    g2l16(Vb + (size_t)r * S_ + cs * 8, &KV[0][1][j * 2048 + dstoff]);
  }

  for (int i = 0; i < 32; ++i) {
    const int cur = i & 1, nxt = cur ^ 1;
    __syncthreads();  // implicit vmcnt(0): slot[cur] DMA (issued last iter) landed
    if (i < 31) {
      const int kvn = (i + 1) * 64;
#pragma unroll
      for (int j = 0; j < 2; ++j) {
        int r = j * 32 + srow;
        g2l16(Kb + (size_t)(kvn + r) * DK_ + cs * 8, &KV[nxt][0][j * 2048 + dstoff]);
        g2l16(Vb + (size_t)r * S_ + kvn + cs * 8, &KV[nxt][1][j * 2048 + dstoff]);
      }
    }

    // ---- QK^T swapped: accS[t] = S^T[kk = t*32 + crow][q], crow=(r&3)+8*(r>>2)+4*hi
    f32x16 accS[2] = {};
    __builtin_amdgcn_s_setprio(1);
#pragma unroll
    for (int t = 0; t < 2; ++t)
#pragma unroll
      for (int ds = 0; ds < 4; ++ds) {
        bf16x8 kf = ld16(&KV[cur][0][(t * 32 + l31) * 64 + (((ds * 2 + hi) ^ swz) * 8)]);
        accS[t] = __builtin_amdgcn_mfma_f32_32x32x16_bf16(kf, qf[ds], accS[t], 0, 0, 0);
      }
    __builtin_amdgcn_s_setprio(0);

    // ---- online softmax, lane-local; defer-max (T13, THR=8 in exp2 domain)
    float a[8];
#pragma unroll
    for (int r = 0; r < 8; ++r)
      a[r] = fmaxf(fmaxf(accS[0][r], accS[1][r]), fmaxf(accS[0][r + 8], accS[1][r + 8]));
#pragma unroll
    for (int s = 4; s; s >>= 1)
#pragma unroll
      for (int r = 0; r < s; ++r) a[r] = fmaxf(a[r], a[r + s]);
    i32x2 mm = pl32swap(asi(a[0]), asi(a[0]));
    float mx = fmaxf(asf(mm.x), asf(mm.y)) * SC;
    if (__any(mx > mreg + 8.f)) {
      float mnew = fmaxf(mreg, mx);
      float scl = exp2f(mreg - mnew);
      mreg = mnew;
      lsum *= scl;
#pragma unroll
      for (int r = 0; r < 16; ++r) { accO[0][r] *= scl; accO[1][r] *= scl; }
    }
#pragma unroll
    for (int t = 0; t < 2; ++t)
#pragma unroll
      for (int r = 0; r < 16; ++r)
        accS[t][r] = exp2f(fmaf(accS[t][r], SC, -mreg));  // P in place
#pragma unroll
    for (int r = 0; r < 8; ++r)
      a[r] = (accS[0][r] + accS[1][r]) + (accS[0][r + 8] + accS[1][r + 8]);
#pragma unroll
    for (int s = 4; s; s >>= 1)
#pragma unroll
      for (int r = 0; r < s; ++r) a[r] += a[r + s];
    i32x2 ss = pl32swap(asi(a[0]), asi(a[0]));
    lsum += asf(ss.x) + asf(ss.y);

    // ---- P^T -> PV B-frags via cvt_pk + permlane32_swap (T12)
    bf16x8 pb[4];
#pragma unroll
    for (int t = 0; t < 2; ++t) {
      i32x2 sA = pl32swap(cvtpk(accS[t][0], accS[t][1]), cvtpk(accS[t][4], accS[t][5]));
      i32x2 sB = pl32swap(cvtpk(accS[t][2], accS[t][3]), cvtpk(accS[t][6], accS[t][7]));
      i32x2 sC = pl32swap(cvtpk(accS[t][8], accS[t][9]), cvtpk(accS[t][12], accS[t][13]));
      i32x2 sD = pl32swap(cvtpk(accS[t][10], accS[t][11]), cvtpk(accS[t][14], accS[t][15]));
      union { i32x4 i; bf16x8 h; } u0, u1;
      u0.i = (i32x4){sA.x, sB.x, sA.y, sB.y};  // k-slot 2t:   lo k0..7,  hi k8..15
      u1.i = (i32x4){sC.x, sD.x, sC.y, sD.y};  // k-slot 2t+1: lo k16..23, hi k24..31
      pb[2 * t] = u0.h;
      pb[2 * t + 1] = u1.h;
    }

    // ---- PV swapped: accO[dh] += V^T(32d x 16k) * P^T(16k x 32q)
    __builtin_amdgcn_s_setprio(1);
#pragma unroll
    for (int ks = 0; ks < 4; ++ks)
#pragma unroll
      for (int dh = 0; dh < 2; ++dh) {
        bf16x8 vf = ld16(&KV[cur][1][(dh * 32 + l31) * 64 + (((ks * 2 + hi) ^ swz) * 8)]);
        accO[dh] = __builtin_amdgcn_mfma_f32_32x32x16_bf16(vf, pb[ks], accO[dh], 0, 0, 0);
      }
    __builtin_amdgcn_s_setprio(0);
  }

  // ---- epilogue: ctx[b][s=q0+l31][h*64+d], d = dh*32 + 8g + 4*hi + r
  const float inv = 1.f / lsum;
  const int b = bh >> 4, h = bh & 15;
  u16* crow = ctx + ((size_t)b * S_ + q0 + l31) * DM_ + h * DK_;
#pragma unroll
  for (int dh = 0; dh < 2; ++dh)
#pragma unroll
    for (int g = 0; g < 4; ++g) {
      u16x4 o;
#pragma unroll
      for (int r = 0; r < 4; ++r) o[r] = f2bf(accO[dh][g * 4 + r] * inv);
      *(u16x4*)(crow + dh * 32 + g * 8 + hi * 4) = o;
    }
}

// ---------------- launcher ----------------
// ws high-water: 4 weights (4x2.1MB) + Qh/Kh/Vt (3x16.8) + ctx (16.8) = 75.5 MB
extern "C" void kernel_launch(void* const* d_in, const int* in_sizes, int n_in,
                              void* d_out, int out_size, void* d_ws, size_t ws_size,
                              hipStream_t stream) {
  const float* q  = (const float*)d_in[0];
  const float* k  = (const float*)d_in[1];
  const float* v  = (const float*)d_in[2];
  const float* Wq = (const float*)d_in[3];
  const float* Wk = (const float*)d_in[4];
  const float* Wv = (const float*)d_in[5];
  const float* Wo = (const float*)d_in[6];

  char* ws = (char*)d_ws;
  const size_t SZX = (size_t)M_ * DM_ * 2;   // 16.78 MB bf16 activation
  const size_t SZW = (size_t)DM_ * DM_ * 2;  // 2.10 MB bf16 weight
  u16* Wqt = (u16*)(ws);
  u16* Wkt = (u16*)(ws + SZW);
  u16* Wvt = (u16*)(ws + 2 * SZW);
  u16* Wot = (u16*)(ws + 3 * SZW);
  u16* Qh  = (u16*)(ws + 4 * SZW);
  u16* Kh  = (u16*)(ws + 4 * SZW + SZX);
  u16* Vt  = (u16*)(ws + 4 * SZW + 2 * SZX);
  u16* ctx = (u16*)(ws + 4 * SZW + 3 * SZX);

  wtrans_kernel<<<dim3(16, 16), 256, 0, stream>>>(Wq, Wqt);
  wtrans_kernel<<<dim3(16, 16), 256, 0, stream>>>(Wk, Wkt);
  wtrans_kernel<<<dim3(16, 16), 256, 0, stream>>>(Wv, Wvt);
  wtrans_kernel<<<dim3(16, 16), 256, 0, stream>>>(Wo, Wot);

  // batched QKV: 96 m-blocks (32 per input) x 4 n-blocks = 384 blocks
  gemm256<0><<<dim3(384), 512, 0, stream>>>(q, k, v, nullptr, Wqt, Wkt, Wvt, Qh, Kh, Vt);

  attn_kernel<<<dim3(16, 64), 256, 0, stream>>>(Qh, Kh, Vt, ctx);

  // out-proj: 32 m-blocks x 4 n-blocks = 128 blocks
  gemm256<1><<<dim3(128), 512, 0, stream>>>(nullptr, nullptr, nullptr, ctx,
                                            Wot, nullptr, nullptr, d_out, nullptr, nullptr);
}